// Round 6
// baseline (290.533 us; speedup 1.0000x reference)
//
#include <hip/hip_runtime.h>

// RBF classifier: out = exp(-(||x-c||^2) * exp(-2*log_sigma)) @ W^T + b
// B=16384, D=784, C=2048, OUT=10. All fp32 in/out.
//
// R7: LDS-FREE K-loop (AITER flatmm style). Three rounds of LDS scheduling
// (phase-split R3b, ring-4 R5, ring-2 R6) all pinned at ~32% MfmaUtil:
// per-tile barriers re-sync the waves so the CU-wide LDS-read and MFMA
// windows alternate. Fix: load MFMA fragments DIRECTLY global->registers
// (per-lane base pointer + compile-time k-offsets that fold into the load's
// offset field -> zero addr VALU), 2-deep register pipeline, NO barriers in
// the K-loop -> waves fully independent; L1 dedups wave-pair re-reads.
// 128x128 block tile, 4 waves 2x2 (wave tile 64x64), 3 blocks/CU by VGPR.
// LDS only holds the epilogue Ph (34.8KB). Preps unchanged.

#define B_ROWS 16384
#define D_DIM  784
#define C_DIM  2048
#define NOUT   10
#define KPAD   832
#define NSTEP  26           // KPAD / 32 half-steps

typedef __attribute__((ext_vector_type(8))) __bf16 bf16x8;
typedef __attribute__((ext_vector_type(4))) float  f32x4;
typedef __attribute__((ext_vector_type(4))) unsigned short ushort4v;

__device__ __forceinline__ unsigned short f2bf(float f) {
  union { float f; unsigned int u; } v; v.f = f;
  unsigned int u = v.u;
  return (unsigned short)((u + 0x7fffu + ((u >> 16) & 1u)) >> 16);  // RNE
}

// fp32 row -> bf16 row (padded to KPAD with zeros) + sum of squares.
// one WAVE per row; no LDS, no syncthreads.
__device__ __forceinline__ void conv_row(const float* __restrict__ src,
                                         unsigned short* __restrict__ dst,
                                         float* __restrict__ sq, int row, int lane) {
  const float* s = src + (size_t)row * D_DIM;
  unsigned short* d = dst + (size_t)row * KPAD;
  float acc = 0.f;
#pragma unroll
  for (int c = 0; c < 4; ++c) {
    const int ch = lane + c * 64;           // ushort4 chunk index, 208 total
    if (ch < 196) {
      const float4 v = ((const float4*)s)[ch];
      ushort4v o; o.x = f2bf(v.x); o.y = f2bf(v.y); o.z = f2bf(v.z); o.w = f2bf(v.w);
      *(ushort4v*)(d + ch * 4) = o;
      acc += v.x * v.x + v.y * v.y + v.z * v.z + v.w * v.w;
    } else if (ch < 208) {
      ushort4v z = {0, 0, 0, 0};
      *(ushort4v*)(d + ch * 4) = z;
    }
  }
#pragma unroll
  for (int off = 32; off > 0; off >>= 1) acc += __shfl_down(acc, off);
  if (lane == 0) sq[row] = acc;
}

// one launch for all preprocessing: x rows | centre rows | bias/Wb/scale.
__global__ __launch_bounds__(256) void prep_all(
    const float* __restrict__ x, const float* __restrict__ cen,
    const float* __restrict__ ls, const float* __restrict__ W,
    const float* __restrict__ bias,
    unsigned short* __restrict__ xb, unsigned short* __restrict__ cb,
    unsigned short* __restrict__ wb,
    float* __restrict__ x2, float* __restrict__ c2, float* __restrict__ sc,
    float* __restrict__ out) {
  const int bx = blockIdx.x;
  if (bx < B_ROWS / 4) {
    conv_row(x, xb, x2, bx * 4 + (threadIdx.x >> 6), threadIdx.x & 63);
  } else if (bx < B_ROWS / 4 + C_DIM / 4) {
    conv_row(cen, cb, c2, (bx - B_ROWS / 4) * 4 + (threadIdx.x >> 6), threadIdx.x & 63);
  } else {
    const int i = (bx - (B_ROWS / 4 + C_DIM / 4)) * 256 + threadIdx.x;
    if (i < B_ROWS * NOUT) out[i] = bias[i % NOUT];
    const int j = i - B_ROWS * NOUT;
    if (j >= 0 && j < 16 * C_DIM)
      wb[j] = ((j >> 11) < NOUT) ? f2bf(W[(j >> 11) * C_DIM + (j & 2047)]) : (unsigned short)0;
    const int k = j - 16 * C_DIM;
    if (k >= 0 && k < C_DIM) sc[k] = __expf(-2.f * ls[k]);
  }
}

// --- main fused kernel: 128x128 tile over (B,C), 4 waves 2x2 (64x64 each).
// K-loop: direct global->register fragment loads, NO LDS, NO barriers.
// LDS only for epilogue: Ph[128][136] bf16 (34.8KB) + 1.5KB f32 vectors.
__global__ __launch_bounds__(256, 3) void rbf_main(
    const unsigned short* __restrict__ xb, const unsigned short* __restrict__ cb,
    const unsigned short* __restrict__ wb,
    const float* __restrict__ x2, const float* __restrict__ c2,
    const float* __restrict__ scale, float* __restrict__ out) {
  __shared__ __align__(16) char smem[34816];     // Ph 128 x 136 shorts
  unsigned short* Ph = (unsigned short*)smem;
  __shared__ float x2s[128], c2s[128], scs[128];

  const int tid  = threadIdx.x;
  const int w    = tid >> 6;
  const int lane = tid & 63;
  const int q    = lane >> 4;
  const int l16  = lane & 15;
  const int brow = blockIdx.x * 128;
  const int bcol = blockIdx.y * 128;
  const int wr   = (w >> 1) * 64;  // wave row offset in tile
  const int wc   = (w & 1) * 64;   // wave col offset

  if (tid < 128) x2s[tid] = x2[brow + tid];
  else { c2s[tid - 128] = c2[bcol + tid - 128]; scs[tid - 128] = scale[bcol + tid - 128]; }

  // per-lane fragment base pointers. Fragment for half-step s (K=32) at
  // row r: shorts [s*32 + q*8 .. +8) -> constant byte offset s*64 from base,
  // folds into the global_load offset field (max 25*64 = 1600 < 4096).
  const unsigned short* pA[4];
  const unsigned short* pB[4];
#pragma unroll
  for (int i = 0; i < 4; ++i) {
    pA[i] = xb + (size_t)(brow + wr + i * 16 + l16) * KPAD + q * 8;
    pB[i] = cb + (size_t)(bcol + wc + i * 16 + l16) * KPAD + q * 8;
  }

#define LDSET(A_, B_, S)                                                    \
  _Pragma("unroll")                                                         \
  for (int ii = 0; ii < 4; ++ii) A_[ii] = *(const bf16x8*)(pA[ii] + (S) * 32); \
  _Pragma("unroll")                                                         \
  for (int jj = 0; jj < 4; ++jj) B_[jj] = *(const bf16x8*)(pB[jj] + (S) * 32);

#define MFMA16(A_, B_)                                                      \
  _Pragma("unroll")                                                         \
  for (int ii = 0; ii < 4; ++ii)                                            \
    _Pragma("unroll")                                                       \
    for (int jj = 0; jj < 4; ++jj)                                          \
      acc[ii][jj] = __builtin_amdgcn_mfma_f32_16x16x32_bf16(                \
          A_[ii], B_[jj], acc[ii][jj], 0, 0, 0);

  f32x4 acc[4][4] = {};
  bf16x8 a0[4], b0[4], a1[4], b1[4];   // 2-deep register pipeline

  LDSET(a0, b0, 0)
  LDSET(a1, b1, 1)
#pragma unroll
  for (int s = 0; s < NSTEP; ++s) {
    if ((s & 1) == 0) {
      MFMA16(a0, b0)
      if (s + 2 < NSTEP) { LDSET(a0, b0, s + 2) }
    } else {
      MFMA16(a1, b1)
      if (s + 2 < NSTEP) { LDSET(a1, b1, s + 2) }
    }
  }
#undef LDSET
#undef MFMA16

  __syncthreads();   // x2s/c2s/scs visible; Ph region free (never touched)

  // epilogue 1: d2 -> phi -> Ph (bf16). C/D layout: col=lane&15, row=q*4+r.
#pragma unroll
  for (int i = 0; i < 4; ++i) {
#pragma unroll
    for (int j = 0; j < 4; ++j) {
      const int cl = wc + j * 16 + l16;
      const float c2v = c2s[cl];
      const float sc = scs[cl];
#pragma unroll
      for (int r = 0; r < 4; ++r) {
        const int rl = wr + i * 16 + q * 4 + r;
        float d2 = fmaxf(x2s[rl] + c2v - 2.f * acc[i][j][r], 0.f);
        Ph[rl * 136 + cl] = f2bf(__expf(-d2 * sc));
      }
    }
  }
  __syncthreads();

  // epilogue 2: out_tile(128x10) = Ph(128x128) @ Wb(16-row slice)^T, K=128.
  // wave w handles rows w*32 .. w*32+31 (2 M-frags).
  f32x4 oacc[2] = {};
#pragma unroll
  for (int kk = 0; kk < 4; ++kk) {
    const bf16x8 bw = *(const bf16x8*)&wb[(size_t)l16 * C_DIM + bcol + kk * 32 + q * 8];
#pragma unroll
    for (int mi = 0; mi < 2; ++mi) {
      const bf16x8 ap = *(const bf16x8*)&Ph[(w * 32 + mi * 16 + l16) * 136 + kk * 32 + q * 8];
      oacc[mi] = __builtin_amdgcn_mfma_f32_16x16x32_bf16(ap, bw, oacc[mi], 0, 0, 0);
    }
  }
  if (l16 < NOUT) {
#pragma unroll
    for (int mi = 0; mi < 2; ++mi)
#pragma unroll
      for (int r = 0; r < 4; ++r) {
        const int grow = brow + w * 32 + mi * 16 + q * 4 + r;
        atomicAdd(&out[grow * NOUT + l16], oacc[mi][r]);
      }
  }
}

extern "C" void kernel_launch(void* const* d_in, const int* in_sizes, int n_in,
                              void* d_out, int out_size, void* d_ws, size_t ws_size,
                              hipStream_t stream) {
  const float* x    = (const float*)d_in[0];  // (16384,784)
  const float* cen  = (const float*)d_in[1];  // (2048,784)
  const float* ls   = (const float*)d_in[2];  // (2048,)
  const float* W    = (const float*)d_in[3];  // (10,2048)
  const float* bias = (const float*)d_in[4];  // (10,)
  float* out = (float*)d_out;                 // (16384,10)

  unsigned char* ws = (unsigned char*)d_ws;
  unsigned short* xb  = (unsigned short*)(ws);              // 16384*832*2 = 27,262,976
  unsigned short* cbf = (unsigned short*)(ws + 27262976);   //  2048*832*2 =  3,407,872
  unsigned short* wb  = (unsigned short*)(ws + 30670848);   //   16*2048*2 =     65,536
  float* x2 = (float*)(ws + 30736384);                      // 16384*4
  float* c2 = (float*)(ws + 30801920);                      //  2048*4
  float* sc = (float*)(ws + 30810112);                      //  2048*4   (end 30,818,304)

  const int prep_blocks = B_ROWS / 4 + C_DIM / 4 +
                          (B_ROWS * NOUT + 16 * C_DIM + C_DIM + 255) / 256;
  prep_all<<<prep_blocks, 256, 0, stream>>>(x, cen, ls, W, bias, xb, cbf, wb, x2, c2, sc, out);
  rbf_main<<<dim3(B_ROWS / 128, C_DIM / 128), 256, 0, stream>>>(xb, cbf, wb, x2, c2, sc, out);
}

// Round 7
// 162.671 us; speedup vs baseline: 1.7860x; 1.7860x over previous
//
#include <hip/hip_runtime.h>

// RBF classifier: out = exp(-(||x-c||^2) * exp(-2*log_sigma)) @ W^T + b
// B=16384, D=784, C=2048, OUT=10. All fp32 in/out.
//
// R8 = R6b (256x256, 8 waves 2x4, BK=64 ring-2, free-run tile loop) +
// (1) XCD-grouped dispatch: 1D grid, wgid remap c=wgid%8,m=wgid/8,y=m%8,
//     x=c+8*(m/8) -> each XCD owns disjoint A row-panels and the 8 col-
//     blocks sharing an A panel run consecutively on the SAME XCD ->
//     A staging re-reads become L2 hits instead of L3 streams.
// (2) counted tile wait: {barrier; STG(t+1)->other buf; vmcnt(8); barrier;
//     compute} -- retires exactly tile t's loads, keeps t+1's in flight.
// Evidence: R2/R3b/R6b all ~70us at 32-36% MfmaUtil across 3 different
// schedules; MFMA busy time == 22.4us floor in all -> invariant cost is
// the 426MB staging path (A re-read x8 cross-XCD misses L2). Epilogue,
// preps, XOR swizzle, layouts unchanged (absmax 0 twice).

#define B_ROWS 16384
#define D_DIM  784
#define C_DIM  2048
#define NOUT   10
#define KPAD   832
#define BK     64
#define NT     13            // KPAD / BK

typedef __attribute__((ext_vector_type(8))) __bf16 bf16x8;
typedef __attribute__((ext_vector_type(4))) float  f32x4;
typedef __attribute__((ext_vector_type(4))) unsigned short ushort4v;

__device__ __forceinline__ unsigned short f2bf(float f) {
  union { float f; unsigned int u; } v; v.f = f;
  unsigned int u = v.u;
  return (unsigned short)((u + 0x7fffu + ((u >> 16) & 1u)) >> 16);  // RNE
}

// async global->LDS, 16B per lane. LDS dest = wave-uniform base + lane*16.
__device__ __forceinline__ void async16(const unsigned short* g, unsigned short* l) {
  __builtin_amdgcn_global_load_lds((const __attribute__((address_space(1))) void*)g,
                                   (__attribute__((address_space(3))) void*)l,
                                   16, 0, 0);
}

// fp32 row -> bf16 row (padded to KPAD with zeros) + sum of squares.
__device__ __forceinline__ void conv_row(const float* __restrict__ src,
                                         unsigned short* __restrict__ dst,
                                         float* __restrict__ sq, int row, int lane) {
  const float* s = src + (size_t)row * D_DIM;
  unsigned short* d = dst + (size_t)row * KPAD;
  float acc = 0.f;
#pragma unroll
  for (int c = 0; c < 4; ++c) {
    const int ch = lane + c * 64;           // ushort4 chunk index, 208 total
    if (ch < 196) {
      const float4 v = ((const float4*)s)[ch];
      ushort4v o; o.x = f2bf(v.x); o.y = f2bf(v.y); o.z = f2bf(v.z); o.w = f2bf(v.w);
      *(ushort4v*)(d + ch * 4) = o;
      acc += v.x * v.x + v.y * v.y + v.z * v.z + v.w * v.w;
    } else if (ch < 208) {
      ushort4v z = {0, 0, 0, 0};
      *(ushort4v*)(d + ch * 4) = z;
    }
  }
#pragma unroll
  for (int off = 32; off > 0; off >>= 1) acc += __shfl_down(acc, off);
  if (lane == 0) sq[row] = acc;
}

// one launch for all preprocessing: x rows | centre rows | bias/Wb/scale.
__global__ __launch_bounds__(256) void prep_all(
    const float* __restrict__ x, const float* __restrict__ cen,
    const float* __restrict__ ls, const float* __restrict__ W,
    const float* __restrict__ bias,
    unsigned short* __restrict__ xb, unsigned short* __restrict__ cb,
    unsigned short* __restrict__ wb,
    float* __restrict__ x2, float* __restrict__ c2, float* __restrict__ sc,
    float* __restrict__ out) {
  const int bx = blockIdx.x;
  if (bx < B_ROWS / 4) {
    conv_row(x, xb, x2, bx * 4 + (threadIdx.x >> 6), threadIdx.x & 63);
  } else if (bx < B_ROWS / 4 + C_DIM / 4) {
    conv_row(cen, cb, c2, (bx - B_ROWS / 4) * 4 + (threadIdx.x >> 6), threadIdx.x & 63);
  } else {
    const int i = (bx - (B_ROWS / 4 + C_DIM / 4)) * 256 + threadIdx.x;
    if (i < B_ROWS * NOUT) out[i] = bias[i % NOUT];
    const int j = i - B_ROWS * NOUT;
    if (j >= 0 && j < 16 * C_DIM)
      wb[j] = ((j >> 11) < NOUT) ? f2bf(W[(j >> 11) * C_DIM + (j & 2047)]) : (unsigned short)0;
    const int k = j - 16 * C_DIM;
    if (k >= 0 && k < C_DIM) sc[k] = __expf(-2.f * ls[k]);
  }
}

// --- main fused kernel: 256x256 tile over (B,C), BK=64, 8 waves 2x4
// (wave tile 128x64). LDS: ring-2 stage buffers (64KB each), overlaid in
// the epilogue by Ph[256][264] bf16 (132KB); +3KiB f32 vectors on top.
__global__ __launch_bounds__(512, 2) void rbf_main(
    const unsigned short* __restrict__ xb, const unsigned short* __restrict__ cb,
    const unsigned short* __restrict__ wb,
    const float* __restrict__ x2, const float* __restrict__ c2,
    const float* __restrict__ scale, float* __restrict__ out) {
  __shared__ __align__(16) char smem[138240];   // 135168 Ph (>=131072 ring) + 3KB vec
  unsigned short* Ph = (unsigned short*)smem;   // 256 x 264 shorts
  float* x2s = (float*)(smem + 135168);
  float* c2s = (float*)(smem + 136192);
  float* scs = (float*)(smem + 137216);

  // XCD-grouped remap: hw xcd = wgid % 8 (round-robin). Give each xcd a
  // disjoint set of row-tiles (x = c + 8*xh) and iterate the 8 col-tiles
  // of one A panel consecutively (y = m % 8) so A re-reads hit that xcd's L2.
  const int wgid = blockIdx.x;          // 0..511
  const int cX   = wgid & 7;
  const int m    = wgid >> 3;           // 0..63
  const int ty   = m & 7;               // col tile 0..7
  const int tx   = cX + 8 * (m >> 3);   // row tile 0..63

  const int tid  = threadIdx.x;
  const int w    = tid >> 6;
  const int lane = tid & 63;
  const int q    = lane >> 4;
  const int l16  = lane & 15;
  const int swz  = l16 & 7;
  const int brow = tx * 256;
  const int bcol = ty * 256;
  const int wr   = (w >> 2) * 128;   // wave row offset: 0 or 128
  const int wc   = (w & 3) * 64;     // wave col offset: 0,64,128,192

  // per-tile vectors (x2 for rows, c2/scale for cols)
  if (tid < 256) { c2s[tid] = c2[bcol + tid]; scs[tid] = scale[bcol + tid]; }
  else           { x2s[tid - 256] = x2[brow + tid - 256]; }
  // drain the preload so the vmcnt FIFO below contains ONLY async16 ops
  asm volatile("s_waitcnt vmcnt(0)" ::: "memory");

  // staging: thread t covers (row = r*64 + t/8, k-octet (t&7) ^ (row&7)) per
  // issue r (8KB each; A tile = 4 issues, B tile = 4 issues). XOR swizzle on
  // the GLOBAL source (LDS dest linear, required by global_load_lds), undone
  // on the read side. Row = 64 shorts = 128B = all 32 banks: conflict-free.
  const int srow = tid >> 3;                       // 0..63
  const int skc  = (tid & 7) ^ (srow & 7);
  const unsigned short* gA = xb + (size_t)(brow + srow) * KPAD + skc * 8;
  const unsigned short* gB = cb + (size_t)(bcol + srow) * KPAD + skc * 8;
  const int ldst = w * 512;                        // shorts; +lane*8 implicit

  // one STG = full K-tile (A 4 issues + B 4 issues = 64KB into buf[T&1])
#define STG(T) { unsigned short* bbA = (unsigned short*)(smem + ((T) & 1) * 65536);   \
    unsigned short* bbB = bbA + 16384;                                                \
    const int k0_ = (T) * BK;                                                         \
    async16(gA + k0_,                bbA         + ldst);                             \
    async16(gA + (size_t)64*KPAD  + k0_, bbA + 4096  + ldst);                         \
    async16(gA + (size_t)128*KPAD + k0_, bbA + 8192  + ldst);                         \
    async16(gA + (size_t)192*KPAD + k0_, bbA + 12288 + ldst);                         \
    async16(gB + k0_,                bbB         + ldst);                             \
    async16(gB + (size_t)64*KPAD  + k0_, bbB + 4096  + ldst);                         \
    async16(gB + (size_t)128*KPAD + k0_, bbB + 8192  + ldst);                         \
    async16(gB + (size_t)192*KPAD + k0_, bbB + 12288 + ldst); }

  // prologue: stage tile 0 only (8 loads in flight)
  STG(0);

  f32x4 acc[8][4] = {};

  for (int t = 0; t < NT; ++t) {
    // barrier 1: every wave has finished its reads of buf[(t+1)&1] (tile
    // t-1) -> safe to stage tile t+1 over it.
    __builtin_amdgcn_s_barrier();
    if (t + 1 < NT) STG(t + 1);
    // retire exactly tile t's 8 loads (issued one full tile ago, ~3600cy);
    // tile t+1's 8 stay in flight across the wait and the compute below.
    if (t + 1 < NT) asm volatile("s_waitcnt vmcnt(8)" ::: "memory");
    else            asm volatile("s_waitcnt vmcnt(0)" ::: "memory");
    __builtin_amdgcn_s_barrier();   // all waves see tile t landed

    const unsigned short* As = (const unsigned short*)(smem + (t & 1) * 65536);
    const unsigned short* Bs = As + 16384;
    bf16x8 af0[4], af1[4], bfr[4];
#pragma unroll
    for (int ks = 0; ks < 2; ++ks) {
#pragma unroll
      for (int j = 0; j < 4; ++j)
        bfr[j] = *(const bf16x8*)&Bs[(wc + j * 16 + l16) * 64 + (((ks * 4 + q) ^ swz) << 3)];
#pragma unroll
      for (int ii = 0; ii < 4; ++ii)
        af0[ii] = *(const bf16x8*)&As[(wr + ii * 16 + l16) * 64 + (((ks * 4 + q) ^ swz) << 3)];
#pragma unroll
      for (int ii = 0; ii < 4; ++ii)
        af1[ii] = *(const bf16x8*)&As[(wr + 64 + ii * 16 + l16) * 64 + (((ks * 4 + q) ^ swz) << 3)];
      __builtin_amdgcn_s_setprio(1);
#pragma unroll
      for (int ii = 0; ii < 4; ++ii)
#pragma unroll
        for (int j = 0; j < 4; ++j)
          acc[ii][j] = __builtin_amdgcn_mfma_f32_16x16x32_bf16(af0[ii], bfr[j], acc[ii][j], 0, 0, 0);
#pragma unroll
      for (int ii = 0; ii < 4; ++ii)
#pragma unroll
        for (int j = 0; j < 4; ++j)
          acc[4 + ii][j] = __builtin_amdgcn_mfma_f32_16x16x32_bf16(af1[ii], bfr[j], acc[4 + ii][j], 0, 0, 0);
      __builtin_amdgcn_s_setprio(0);
    }
  }
#undef STG

  __syncthreads();   // full drain; Ph overlays the ring buffers

  // epilogue 1: d2 -> phi -> Ph (bf16). C/D layout: col=lane&15, row=q*4+r.
#pragma unroll
  for (int i = 0; i < 8; ++i) {
#pragma unroll
    for (int j = 0; j < 4; ++j) {
      const int cl = wc + j * 16 + l16;
      const float c2v = c2s[cl];
      const float sc = scs[cl];
#pragma unroll
      for (int r = 0; r < 4; ++r) {
        const int rl = wr + i * 16 + q * 4 + r;
        float d2 = fmaxf(x2s[rl] + c2v - 2.f * acc[i][j][r], 0.f);
        Ph[rl * 264 + cl] = f2bf(__expf(-d2 * sc));
      }
    }
  }
  __syncthreads();

  // epilogue 2: out_tile(256x10) = Ph(256x256) @ Wb(16-row slice)^T, K=256.
  // wave w handles rows w*32 .. w*32+31 (2 M-frags).
  f32x4 oacc[2] = {};
#pragma unroll
  for (int kk = 0; kk < 8; ++kk) {
    const bf16x8 bw = *(const bf16x8*)&wb[(size_t)l16 * C_DIM + bcol + kk * 32 + q * 8];
#pragma unroll
    for (int mi = 0; mi < 2; ++mi) {
      const bf16x8 ap = *(const bf16x8*)&Ph[(w * 32 + mi * 16 + l16) * 264 + kk * 32 + q * 8];
      oacc[mi] = __builtin_amdgcn_mfma_f32_16x16x32_bf16(ap, bw, oacc[mi], 0, 0, 0);
    }
  }
  if (l16 < NOUT) {
#pragma unroll
    for (int mi = 0; mi < 2; ++mi)
#pragma unroll
      for (int r = 0; r < 4; ++r) {
        const int grow = brow + w * 32 + mi * 16 + q * 4 + r;
        atomicAdd(&out[grow * NOUT + l16], oacc[mi][r]);
      }
  }
}

extern "C" void kernel_launch(void* const* d_in, const int* in_sizes, int n_in,
                              void* d_out, int out_size, void* d_ws, size_t ws_size,
                              hipStream_t stream) {
  const float* x    = (const float*)d_in[0];  // (16384,784)
  const float* cen  = (const float*)d_in[1];  // (2048,784)
  const float* ls   = (const float*)d_in[2];  // (2048,)
  const float* W    = (const float*)d_in[3];  // (10,2048)
  const float* bias = (const float*)d_in[4];  // (10,)
  float* out = (float*)d_out;                 // (16384,10)

  unsigned char* ws = (unsigned char*)d_ws;
  unsigned short* xb  = (unsigned short*)(ws);              // 16384*832*2 = 27,262,976
  unsigned short* cbf = (unsigned short*)(ws + 27262976);   //  2048*832*2 =  3,407,872
  unsigned short* wb  = (unsigned short*)(ws + 30670848);   //   16*2048*2 =     65,536
  float* x2 = (float*)(ws + 30736384);                      // 16384*4
  float* c2 = (float*)(ws + 30801920);                      //  2048*4
  float* sc = (float*)(ws + 30810112);                      //  2048*4   (end 30,818,304)

  const int prep_blocks = B_ROWS / 4 + C_DIM / 4 +
                          (B_ROWS * NOUT + 16 * C_DIM + C_DIM + 255) / 256;
  prep_all<<<prep_blocks, 256, 0, stream>>>(x, cen, ls, W, bias, xb, cbf, wb, x2, c2, sc, out);
  rbf_main<<<512, 512, 0, stream>>>(xb, cbf, wb, x2, c2, sc, out);
}

// Round 8
// 159.652 us; speedup vs baseline: 1.8198x; 1.0189x over previous
//
#include <hip/hip_runtime.h>

// RBF classifier: out = exp(-(||x-c||^2) * exp(-2*log_sigma)) @ W^T + b
// B=16384, D=784, C=2048, OUT=10. All fp32 in/out.
//
// R9 = R6b (256x256, 8 waves 2x4, BK=64 ring-2, 1 barrier + vmcnt/tile)
// with ONE change: 1D dispatch, ty = wgid%8 (= hw XCD id), tx = wgid/8.
// Each XCD owns exactly one B col-panel (426KB -> L2-resident all kernel)
// and streams A read-once. Halves L3 staging traffic 436->218MB.
// Model: R3b/R6b/R8 all ran staging at ~6 TB/s (L3 feed ceiling, 10 B/cy/CU
// = 64KB/6400cy per tile) -- L3-BW-bound, which is why every schedule landed
// at ~70us. R2's 128^2 was L2-resident (13 TB/s) but structure-stalled.

#define B_ROWS 16384
#define D_DIM  784
#define C_DIM  2048
#define NOUT   10
#define KPAD   832
#define BK     64
#define NT     13            // KPAD / BK

typedef __attribute__((ext_vector_type(8))) __bf16 bf16x8;
typedef __attribute__((ext_vector_type(4))) float  f32x4;
typedef __attribute__((ext_vector_type(4))) unsigned short ushort4v;

__device__ __forceinline__ unsigned short f2bf(float f) {
  union { float f; unsigned int u; } v; v.f = f;
  unsigned int u = v.u;
  return (unsigned short)((u + 0x7fffu + ((u >> 16) & 1u)) >> 16);  // RNE
}

// async global->LDS, 16B per lane. LDS dest = wave-uniform base + lane*16.
__device__ __forceinline__ void async16(const unsigned short* g, unsigned short* l) {
  __builtin_amdgcn_global_load_lds((const __attribute__((address_space(1))) void*)g,
                                   (__attribute__((address_space(3))) void*)l,
                                   16, 0, 0);
}

// fp32 row -> bf16 row (padded to KPAD with zeros) + sum of squares.
__device__ __forceinline__ void conv_row(const float* __restrict__ src,
                                         unsigned short* __restrict__ dst,
                                         float* __restrict__ sq, int row, int lane) {
  const float* s = src + (size_t)row * D_DIM;
  unsigned short* d = dst + (size_t)row * KPAD;
  float acc = 0.f;
#pragma unroll
  for (int c = 0; c < 4; ++c) {
    const int ch = lane + c * 64;           // ushort4 chunk index, 208 total
    if (ch < 196) {
      const float4 v = ((const float4*)s)[ch];
      ushort4v o; o.x = f2bf(v.x); o.y = f2bf(v.y); o.z = f2bf(v.z); o.w = f2bf(v.w);
      *(ushort4v*)(d + ch * 4) = o;
      acc += v.x * v.x + v.y * v.y + v.z * v.z + v.w * v.w;
    } else if (ch < 208) {
      ushort4v z = {0, 0, 0, 0};
      *(ushort4v*)(d + ch * 4) = z;
    }
  }
#pragma unroll
  for (int off = 32; off > 0; off >>= 1) acc += __shfl_down(acc, off);
  if (lane == 0) sq[row] = acc;
}

// one launch for all preprocessing: x rows | centre rows | bias/Wb/scale.
__global__ __launch_bounds__(256) void prep_all(
    const float* __restrict__ x, const float* __restrict__ cen,
    const float* __restrict__ ls, const float* __restrict__ W,
    const float* __restrict__ bias,
    unsigned short* __restrict__ xb, unsigned short* __restrict__ cb,
    unsigned short* __restrict__ wb,
    float* __restrict__ x2, float* __restrict__ c2, float* __restrict__ sc,
    float* __restrict__ out) {
  const int bx = blockIdx.x;
  if (bx < B_ROWS / 4) {
    conv_row(x, xb, x2, bx * 4 + (threadIdx.x >> 6), threadIdx.x & 63);
  } else if (bx < B_ROWS / 4 + C_DIM / 4) {
    conv_row(cen, cb, c2, (bx - B_ROWS / 4) * 4 + (threadIdx.x >> 6), threadIdx.x & 63);
  } else {
    const int i = (bx - (B_ROWS / 4 + C_DIM / 4)) * 256 + threadIdx.x;
    if (i < B_ROWS * NOUT) out[i] = bias[i % NOUT];
    const int j = i - B_ROWS * NOUT;
    if (j >= 0 && j < 16 * C_DIM)
      wb[j] = ((j >> 11) < NOUT) ? f2bf(W[(j >> 11) * C_DIM + (j & 2047)]) : (unsigned short)0;
    const int k = j - 16 * C_DIM;
    if (k >= 0 && k < C_DIM) sc[k] = __expf(-2.f * ls[k]);
  }
}

// --- main fused kernel: 256x256 tile over (B,C), BK=64, 8 waves 2x4
// (wave tile 128x64). LDS: ring-2 stage buffers (64KB each), overlaid in
// the epilogue by Ph[256][264] bf16 (132KB); +3KiB f32 vectors on top.
__global__ __launch_bounds__(512, 2) void rbf_main(
    const unsigned short* __restrict__ xb, const unsigned short* __restrict__ cb,
    const unsigned short* __restrict__ wb,
    const float* __restrict__ x2, const float* __restrict__ c2,
    const float* __restrict__ scale, float* __restrict__ out) {
  __shared__ __align__(16) char smem[138240];   // 135168 Ph (>=131072 ring) + 3KB vec
  unsigned short* Ph = (unsigned short*)smem;   // 256 x 264 shorts
  float* x2s = (float*)(smem + 135168);
  float* c2s = (float*)(smem + 136192);
  float* scs = (float*)(smem + 137216);

  // XCD-resident-B remap: hw xcd = wgid % 8 (round-robin, m09). There are
  // exactly 8 col-tiles (C=2048 / 256), so give XCD c ALL blocks of col-tile
  // c: its 426KB B-panel stays L2-resident for the whole kernel; A-panels
  // stream read-once. Halves L3 staging traffic vs any mixed mapping.
  const int wgid = blockIdx.x;          // 0..511
  const int ty   = wgid & 7;            // col tile == XCD id
  const int tx   = wgid >> 3;           // row tile 0..63

  const int tid  = threadIdx.x;
  const int w    = tid >> 6;
  const int lane = tid & 63;
  const int q    = lane >> 4;
  const int l16  = lane & 15;
  const int swz  = l16 & 7;
  const int brow = tx * 256;
  const int bcol = ty * 256;
  const int wr   = (w >> 2) * 128;   // wave row offset: 0 or 128
  const int wc   = (w & 3) * 64;     // wave col offset: 0,64,128,192

  // per-tile vectors (x2 for rows, c2/scale for cols)
  if (tid < 256) { c2s[tid] = c2[bcol + tid]; scs[tid] = scale[bcol + tid]; }
  else           { x2s[tid - 256] = x2[brow + tid - 256]; }
  // drain the preload so the vmcnt FIFO below contains ONLY async16 ops
  asm volatile("s_waitcnt vmcnt(0)" ::: "memory");

  // staging: thread t covers (row = r*64 + t/8, k-octet (t&7) ^ (row&7)) per
  // issue r (8KB each; A tile = 4 issues, B tile = 4 issues). XOR swizzle on
  // the GLOBAL source (LDS dest linear, required by global_load_lds), undone
  // on the read side. Row = 64 shorts = 128B = all 32 banks: conflict-free.
  const int srow = tid >> 3;                       // 0..63
  const int skc  = (tid & 7) ^ (srow & 7);
  const unsigned short* gA = xb + (size_t)(brow + srow) * KPAD + skc * 8;
  const unsigned short* gB = cb + (size_t)(bcol + srow) * KPAD + skc * 8;
  const int ldst = w * 512;                        // shorts; +lane*8 implicit

  // one STG = full K-tile (A 4 issues + B 4 issues = 64KB into buf[T&1])
#define STG(T) { unsigned short* bbA = (unsigned short*)(smem + ((T) & 1) * 65536);   \
    unsigned short* bbB = bbA + 16384;                                                \
    const int k0_ = (T) * BK;                                                         \
    async16(gA + k0_,                bbA         + ldst);                             \
    async16(gA + (size_t)64*KPAD  + k0_, bbA + 4096  + ldst);                         \
    async16(gA + (size_t)128*KPAD + k0_, bbA + 8192  + ldst);                         \
    async16(gA + (size_t)192*KPAD + k0_, bbA + 12288 + ldst);                         \
    async16(gB + k0_,                bbB         + ldst);                             \
    async16(gB + (size_t)64*KPAD  + k0_, bbB + 4096  + ldst);                         \
    async16(gB + (size_t)128*KPAD + k0_, bbB + 8192  + ldst);                         \
    async16(gB + (size_t)192*KPAD + k0_, bbB + 12288 + ldst); }

  // prologue: stage tiles 0 and 1 (16 issues in flight)
  STG(0); STG(1);

  f32x4 acc[8][4] = {};

  for (int t = 0; t < NT; ++t) {
    // entry: tile t must have landed. t=0: keep tile 1's 8 in flight.
    // t>=1: the 8 outstanding are tile t's own, issued a full tile ago.
    if (t == 0) asm volatile("s_waitcnt vmcnt(8)" ::: "memory");
    else        asm volatile("s_waitcnt vmcnt(0)" ::: "memory");
    __builtin_amdgcn_s_barrier();   // raw: in-flight counted loads survive

    // stage t+1 into buf[(t+1)&1]: every wave passing the barrier has
    // register-consumed its reads of that buffer (tile t-1) -> WAR-safe.
    if (t >= 1 && t < NT - 1) STG(t + 1);

    const unsigned short* As = (const unsigned short*)(smem + (t & 1) * 65536);
    const unsigned short* Bs = As + 16384;
    bf16x8 af0[4], af1[4], bfr[4];
#pragma unroll
    for (int ks = 0; ks < 2; ++ks) {
#pragma unroll
      for (int j = 0; j < 4; ++j)
        bfr[j] = *(const bf16x8*)&Bs[(wc + j * 16 + l16) * 64 + (((ks * 4 + q) ^ swz) << 3)];
#pragma unroll
      for (int ii = 0; ii < 4; ++ii)
        af0[ii] = *(const bf16x8*)&As[(wr + ii * 16 + l16) * 64 + (((ks * 4 + q) ^ swz) << 3)];
#pragma unroll
      for (int ii = 0; ii < 4; ++ii)
        af1[ii] = *(const bf16x8*)&As[(wr + 64 + ii * 16 + l16) * 64 + (((ks * 4 + q) ^ swz) << 3)];
      __builtin_amdgcn_s_setprio(1);
#pragma unroll
      for (int ii = 0; ii < 4; ++ii)
#pragma unroll
        for (int j = 0; j < 4; ++j)
          acc[ii][j] = __builtin_amdgcn_mfma_f32_16x16x32_bf16(af0[ii], bfr[j], acc[ii][j], 0, 0, 0);
#pragma unroll
      for (int ii = 0; ii < 4; ++ii)
#pragma unroll
        for (int j = 0; j < 4; ++j)
          acc[4 + ii][j] = __builtin_amdgcn_mfma_f32_16x16x32_bf16(af1[ii], bfr[j], acc[4 + ii][j], 0, 0, 0);
      __builtin_amdgcn_s_setprio(0);
    }
  }
#undef STG

  __syncthreads();   // full drain; Ph overlays the ring buffers

  // epilogue 1: d2 -> phi -> Ph (bf16). C/D layout: col=lane&15, row=q*4+r.
#pragma unroll
  for (int i = 0; i < 8; ++i) {
#pragma unroll
    for (int j = 0; j < 4; ++j) {
      const int cl = wc + j * 16 + l16;
      const float c2v = c2s[cl];
      const float sc = scs[cl];
#pragma unroll
      for (int r = 0; r < 4; ++r) {
        const int rl = wr + i * 16 + q * 4 + r;
        float d2 = fmaxf(x2s[rl] + c2v - 2.f * acc[i][j][r], 0.f);
        Ph[rl * 264 + cl] = f2bf(__expf(-d2 * sc));
      }
    }
  }
  __syncthreads();

  // epilogue 2: out_tile(256x10) = Ph(256x256) @ Wb(16-row slice)^T, K=256.
  // wave w handles rows w*32 .. w*32+31 (2 M-frags).
  f32x4 oacc[2] = {};
#pragma unroll
  for (int kk = 0; kk < 8; ++kk) {
    const bf16x8 bw = *(const bf16x8*)&wb[(size_t)l16 * C_DIM + bcol + kk * 32 + q * 8];
#pragma unroll
    for (int mi = 0; mi < 2; ++mi) {
      const bf16x8 ap = *(const bf16x8*)&Ph[(w * 32 + mi * 16 + l16) * 264 + kk * 32 + q * 8];
      oacc[mi] = __builtin_amdgcn_mfma_f32_16x16x32_bf16(ap, bw, oacc[mi], 0, 0, 0);
    }
  }
  if (l16 < NOUT) {
#pragma unroll
    for (int mi = 0; mi < 2; ++mi)
#pragma unroll
      for (int r = 0; r < 4; ++r) {
        const int grow = brow + w * 32 + mi * 16 + q * 4 + r;
        atomicAdd(&out[grow * NOUT + l16], oacc[mi][r]);
      }
  }
}

extern "C" void kernel_launch(void* const* d_in, const int* in_sizes, int n_in,
                              void* d_out, int out_size, void* d_ws, size_t ws_size,
                              hipStream_t stream) {
  const float* x    = (const float*)d_in[0];  // (16384,784)
  const float* cen  = (const float*)d_in[1];  // (2048,784)
  const float* ls   = (const float*)d_in[2];  // (2048,)
  const float* W    = (const float*)d_in[3];  // (10,2048)
  const float* bias = (const float*)d_in[4];  // (10,)
  float* out = (float*)d_out;                 // (16384,10)

  unsigned char* ws = (unsigned char*)d_ws;
  unsigned short* xb  = (unsigned short*)(ws);              // 16384*832*2 = 27,262,976
  unsigned short* cbf = (unsigned short*)(ws + 27262976);   //  2048*832*2 =  3,407,872
  unsigned short* wb  = (unsigned short*)(ws + 30670848);   //   16*2048*2 =     65,536
  float* x2 = (float*)(ws + 30736384);                      // 16384*4
  float* c2 = (float*)(ws + 30801920);                      //  2048*4
  float* sc = (float*)(ws + 30810112);                      //  2048*4   (end 30,818,304)

  const int prep_blocks = B_ROWS / 4 + C_DIM / 4 +
                          (B_ROWS * NOUT + 16 * C_DIM + C_DIM + 255) / 256;
  prep_all<<<prep_blocks, 256, 0, stream>>>(x, cen, ls, W, bias, xb, cbf, wb, x2, c2, sc, out);
  rbf_main<<<512, 512, 0, stream>>>(xb, cbf, wb, x2, c2, sc, out);
}

// Round 11
// 158.790 us; speedup vs baseline: 1.8297x; 1.0054x over previous
//
#include <hip/hip_runtime.h>

// RBF classifier: out = exp(-(||x-c||^2) * exp(-2*log_sigma)) @ W^T + b
// B=16384, D=784, C=2048, OUT=10. All fp32 in/out.
//
// R10c: functionally identical to R10/R10b (both died at container level
// with zero kernel evidence; session infra failure rate 4/11). Header text
// changed to break any source-keyed artifact caching. Components are both
// session-proven: rbf_main == Round-0 kernel (166us pass, 66.9us main),
// prep_all == R3b..R9 prep (six clean runs). Structure: 128x128 tile,
// 4 waves 2x2, BK=64, single-buffered union LDS 36.3KB -> 4 blocks/CU
// (cross-block LDS/MFMA pipe overlap), plain __syncthreads only.

#define B_ROWS 16384
#define D_DIM  784
#define C_DIM  2048
#define NOUT   10
#define KPAD   832
#define BK     64

typedef __attribute__((ext_vector_type(8))) __bf16 bf16x8;
typedef __attribute__((ext_vector_type(4))) float  f32x4;
typedef __attribute__((ext_vector_type(4))) unsigned short ushort4v;

__device__ __forceinline__ unsigned short f2bf(float f) {
  union { float f; unsigned int u; } v; v.f = f;
  unsigned int u = v.u;
  return (unsigned short)((u + 0x7fffu + ((u >> 16) & 1u)) >> 16);  // RNE
}

// async global->LDS, 16B per lane. LDS dest = wave-uniform base + lane*16.
__device__ __forceinline__ void async16(const unsigned short* g, unsigned short* l) {
  __builtin_amdgcn_global_load_lds((const __attribute__((address_space(1))) void*)g,
                                   (__attribute__((address_space(3))) void*)l,
                                   16, 0, 0);
}

// fp32 row -> bf16 row (padded to KPAD with zeros) + sum of squares.
// one WAVE per row; no LDS, no syncthreads.
__device__ __forceinline__ void conv_row(const float* __restrict__ src,
                                         unsigned short* __restrict__ dst,
                                         float* __restrict__ sq, int row, int lane) {
  const float* s = src + (size_t)row * D_DIM;
  unsigned short* d = dst + (size_t)row * KPAD;
  float acc = 0.f;
#pragma unroll
  for (int c = 0; c < 4; ++c) {
    const int ch = lane + c * 64;           // ushort4 chunk index, 208 total
    if (ch < 196) {
      const float4 v = ((const float4*)s)[ch];
      ushort4v o; o.x = f2bf(v.x); o.y = f2bf(v.y); o.z = f2bf(v.z); o.w = f2bf(v.w);
      *(ushort4v*)(d + ch * 4) = o;
      acc += v.x * v.x + v.y * v.y + v.z * v.z + v.w * v.w;
    } else if (ch < 208) {
      ushort4v z = {0, 0, 0, 0};
      *(ushort4v*)(d + ch * 4) = z;
    }
  }
#pragma unroll
  for (int off = 32; off > 0; off >>= 1) acc += __shfl_down(acc, off);
  if (lane == 0) sq[row] = acc;
}

// one launch for all preprocessing: x rows | centre rows | bias/Wb/scale.
__global__ __launch_bounds__(256) void prep_all(
    const float* __restrict__ x, const float* __restrict__ cen,
    const float* __restrict__ ls, const float* __restrict__ W,
    const float* __restrict__ bias,
    unsigned short* __restrict__ xb, unsigned short* __restrict__ cb,
    unsigned short* __restrict__ wb,
    float* __restrict__ x2, float* __restrict__ c2, float* __restrict__ sc,
    float* __restrict__ out) {
  const int bx = blockIdx.x;
  if (bx < B_ROWS / 4) {
    conv_row(x, xb, x2, bx * 4 + (threadIdx.x >> 6), threadIdx.x & 63);
  } else if (bx < B_ROWS / 4 + C_DIM / 4) {
    conv_row(cen, cb, c2, (bx - B_ROWS / 4) * 4 + (threadIdx.x >> 6), threadIdx.x & 63);
  } else {
    const int i = (bx - (B_ROWS / 4 + C_DIM / 4)) * 256 + threadIdx.x;
    if (i < B_ROWS * NOUT) out[i] = bias[i % NOUT];
    const int j = i - B_ROWS * NOUT;
    if (j >= 0 && j < 16 * C_DIM)
      wb[j] = ((j >> 11) < NOUT) ? f2bf(W[(j >> 11) * C_DIM + (j & 2047)]) : (unsigned short)0;
    const int k = j - 16 * C_DIM;
    if (k >= 0 && k < C_DIM) sc[k] = __expf(-2.f * ls[k]);
  }
}

// --- main fused kernel: 128x128 tile over (B,C), BK=64, 4 waves 2x2.
// LDS union: [ As(16K) | Bs(16K) ] overlaid by Ph(34K); + 1.5K f32 vectors.
// 36.3KB total -> 4 blocks/CU: cross-block LDS/MFMA pipe overlap.
__global__ __launch_bounds__(256, 4) void rbf_main(
    const unsigned short* __restrict__ xb, const unsigned short* __restrict__ cb,
    const unsigned short* __restrict__ wb,
    const float* __restrict__ x2, const float* __restrict__ c2,
    const float* __restrict__ scale, float* __restrict__ out) {
  __shared__ char smem[34816];               // max(32768 stage, 34816 Ph)
  unsigned short* As = (unsigned short*)smem;            // 128 x 64 shorts
  unsigned short* Bs = (unsigned short*)(smem + 16384);  // 128 x 64 shorts
  unsigned short* Ph = (unsigned short*)smem;            // 128 x 136 shorts
  __shared__ float x2s[128], c2s[128], scs[128];

  const int tid  = threadIdx.x;
  const int w    = tid >> 6;
  const int lane = tid & 63;
  const int q    = lane >> 4;
  const int l16  = lane & 15;
  const int brow = blockIdx.x * 128;
  const int bcol = blockIdx.y * 128;

  if (tid < 128) x2s[tid] = x2[brow + tid];
  else { c2s[tid - 128] = c2[bcol + tid - 128]; scs[tid - 128] = scale[bcol + tid - 128]; }

  // staging: thread t covers (row = r*32 + t/8, k-chunk = (t&7) ^ (row&7)) per
  // issue r. XOR swizzle keeps read side conflict-even at 128B row stride.
  const int srow = tid >> 3;                       // 0..31
  const int skc  = (tid & 7) ^ (srow & 7);         // swizzled k-chunk
  const unsigned short* gA = xb + (size_t)(brow + srow) * KPAD + skc * 8;
  const unsigned short* gB = cb + (size_t)(bcol + srow) * KPAD + skc * 8;
  unsigned short* lA = &As[w * 512];               // + r*2048 per issue
  unsigned short* lB = &Bs[w * 512];

  const int wr = (w >> 1) * 64;  // wave row offset in tile
  const int wc = (w & 1) * 64;   // wave col offset
  const int swz = l16 & 7;

  f32x4 acc[4][4] = {};

  for (int k0 = 0; k0 < KPAD; k0 += BK) {
#pragma unroll
    for (int r = 0; r < 4; ++r) {
      async16(gA + (size_t)r * 32 * KPAD + k0, lA + r * 2048);
      async16(gB + (size_t)r * 32 * KPAD + k0, lB + r * 2048);
    }
    __syncthreads();  // drains vmcnt (global_load_lds) per barrier semantics
#pragma unroll
    for (int ks = 0; ks < 2; ++ks) {
      bf16x8 af[4], bfr[4];
#pragma unroll
      for (int i = 0; i < 4; ++i)
        af[i] = *(const bf16x8*)&As[(wr + i * 16 + l16) * 64 + (((ks * 4 + q) ^ swz) << 3)];
#pragma unroll
      for (int j = 0; j < 4; ++j)
        bfr[j] = *(const bf16x8*)&Bs[(wc + j * 16 + l16) * 64 + (((ks * 4 + q) ^ swz) << 3)];
#pragma unroll
      for (int i = 0; i < 4; ++i)
#pragma unroll
        for (int j = 0; j < 4; ++j)
          acc[i][j] = __builtin_amdgcn_mfma_f32_16x16x32_bf16(af[i], bfr[j], acc[i][j], 0, 0, 0);
    }
    __syncthreads();
  }

  // epilogue 1: d2 -> phi -> Ph (bf16), overlaying the dead stage buffers.
  // C/D layout: col=lane&15, row=q*4+r.
#pragma unroll
  for (int i = 0; i < 4; ++i) {
#pragma unroll
    for (int j = 0; j < 4; ++j) {
      const int cl = wc + j * 16 + l16;
      const float c2v = c2s[cl];
      const float sc = scs[cl];
#pragma unroll
      for (int r = 0; r < 4; ++r) {
        const int rl = wr + i * 16 + q * 4 + r;
        float d2 = x2s[rl] + c2v - 2.f * acc[i][j][r];
        d2 = fmaxf(d2, 0.f);
        const float phi = __expf(-d2 * sc);
        Ph[rl * 136 + cl] = f2bf(phi);
      }
    }
  }
  __syncthreads();

  // epilogue 2: out_tile(128x10) = Ph(128x128) @ Wb(16-row slice)^T, K=128.
  // wave w handles rows w*32 .. w*32+31 (2 M-frags).
  f32x4 oacc[2] = {};
#pragma unroll
  for (int kk = 0; kk < 4; ++kk) {
    const bf16x8 bw = *(const bf16x8*)&wb[(size_t)l16 * C_DIM + bcol + kk * 32 + q * 8];
#pragma unroll
    for (int mi = 0; mi < 2; ++mi) {
      const bf16x8 ap = *(const bf16x8*)&Ph[(w * 32 + mi * 16 + l16) * 136 + kk * 32 + q * 8];
      oacc[mi] = __builtin_amdgcn_mfma_f32_16x16x32_bf16(ap, bw, oacc[mi], 0, 0, 0);
    }
  }
  if (l16 < NOUT) {
#pragma unroll
    for (int mi = 0; mi < 2; ++mi)
#pragma unroll
      for (int r = 0; r < 4; ++r) {
        const int grow = brow + w * 32 + mi * 16 + q * 4 + r;
        atomicAdd(&out[grow * NOUT + l16], oacc[mi][r]);
      }
  }
}

extern "C" void kernel_launch(void* const* d_in, const int* in_sizes, int n_in,
                              void* d_out, int out_size, void* d_ws, size_t ws_size,
                              hipStream_t stream) {
  const float* x    = (const float*)d_in[0];  // (16384,784)
  const float* cen  = (const float*)d_in[1];  // (2048,784)
  const float* ls   = (const float*)d_in[2];  // (2048,)
  const float* W    = (const float*)d_in[3];  // (10,2048)
  const float* bias = (const float*)d_in[4];  // (10,)
  float* out = (float*)d_out;                 // (16384,10)

  unsigned char* ws = (unsigned char*)d_ws;
  unsigned short* xb  = (unsigned short*)(ws);              // 16384*832*2 = 27,262,976
  unsigned short* cbf = (unsigned short*)(ws + 27262976);   //  2048*832*2 =  3,407,872
  unsigned short* wb  = (unsigned short*)(ws + 30670848);   //   16*2048*2 =     65,536
  float* x2 = (float*)(ws + 30736384);                      // 16384*4
  float* c2 = (float*)(ws + 30801920);                      //  2048*4
  float* sc = (float*)(ws + 30810112);                      //  2048*4   (end 30,818,304)

  const int prep_blocks = B_ROWS / 4 + C_DIM / 4 +
                          (B_ROWS * NOUT + 16 * C_DIM + C_DIM + 255) / 256;
  prep_all<<<prep_blocks, 256, 0, stream>>>(x, cen, ls, W, bias, xb, cbf, wb, x2, c2, sc, out);
  rbf_main<<<dim3(B_ROWS / 128, C_DIM / 128), 256, 0, stream>>>(xb, cbf, wb, x2, c2, sc, out);
}

// Round 12
// 142.439 us; speedup vs baseline: 2.0397x; 1.1148x over previous
//
#include <hip/hip_runtime.h>

// RBF classifier: out = exp(-(||x-c||^2) * exp(-2*log_sigma)) @ W^T + b
// B=16384, D=784, C=2048, OUT=10. All fp32 in/out.
//
// R11: INT8 main GEMM on the proven R2/R10c structure (128x128 tile, 4 waves
// 2x2, single-buffered union LDS 36.3KB -> 4 blocks/CU, 2 syncthreads/tile).
// R10c confirmed we sit exactly at the m97-structure ceiling (55.8GF / 912TF
// = 61us + 4 epilogue = 65 measured); 4 attempts at the 8-phase escape all
// failed. The documented remaining lever is precision: mfma_i32_16x16x64_i8
// = 2x bf16 rate, K=64/instr. x,c quantized to i8 (scale 4/127; norms stay
// exact fp32; only the cross term is quantized -- d2 err ~1e0 on ~1.5e3).
// BK=128 i8 = 128B LDS rows -> identical proven XOR-octet swizzle (16B
// octets). Tiles 13->7, staging/LDS/MFMA all halve. Epilogue bf16 unchanged.

#define B_ROWS 16384
#define D_DIM  784
#define C_DIM  2048
#define NOUT   10
#define KPAD   896           // i8 K padded to 7 x 128
#define BK     128
#define NT     7

typedef __attribute__((ext_vector_type(8))) __bf16 bf16x8;
typedef __attribute__((ext_vector_type(4))) float  f32x4;
typedef __attribute__((ext_vector_type(4))) int    i32x4;

#define QSCALE_INV 31.75f                  // 127/4: clip at 4 sigma
#define TWO_S2 (2.0f * (4.0f/127.0f) * (4.0f/127.0f))

__device__ __forceinline__ unsigned short f2bf(float f) {
  union { float f; unsigned int u; } v; v.f = f;
  unsigned int u = v.u;
  return (unsigned short)((u + 0x7fffu + ((u >> 16) & 1u)) >> 16);  // RNE
}

// async global->LDS, 16B per lane. LDS dest = wave-uniform base + lane*16.
__device__ __forceinline__ void async16(const void* g, void* l) {
  __builtin_amdgcn_global_load_lds((const __attribute__((address_space(1))) void*)g,
                                   (__attribute__((address_space(3))) void*)l,
                                   16, 0, 0);
}

__device__ __forceinline__ int q8(float v) {
  return __float2int_rn(fminf(fmaxf(v, -4.f), 4.f) * QSCALE_INV);
}

// fp32 row -> i8 row (padded to KPAD zeros) + fp32 sum of squares.
// one WAVE per row (4 rows / 256-thr block); no LDS, no syncthreads.
__device__ __forceinline__ void conv_row(const float* __restrict__ src,
                                         signed char* __restrict__ dst,
                                         float* __restrict__ sq, int row, int lane) {
  const float* s = src + (size_t)row * D_DIM;
  unsigned int* d = (unsigned int*)(dst + (size_t)row * KPAD);
  float acc = 0.f;
#pragma unroll
  for (int c = 0; c < 4; ++c) {
    const int ch = lane + c * 64;           // uint (4-byte) chunk, 224 total
    if (ch < 196) {
      const float4 v = ((const float4*)s)[ch];
      const unsigned int b = (unsigned int)(q8(v.x) & 255) |
                             ((unsigned int)(q8(v.y) & 255) << 8) |
                             ((unsigned int)(q8(v.z) & 255) << 16) |
                             ((unsigned int)(q8(v.w) & 255) << 24);
      d[ch] = b;
      acc += v.x * v.x + v.y * v.y + v.z * v.z + v.w * v.w;
    } else if (ch < 224) {
      d[ch] = 0u;
    }
  }
#pragma unroll
  for (int off = 32; off > 0; off >>= 1) acc += __shfl_down(acc, off);
  if (lane == 0) sq[row] = acc;
}

// one launch for all preprocessing: x rows | centre rows | bias/Wb/scale.
__global__ __launch_bounds__(256) void prep_all(
    const float* __restrict__ x, const float* __restrict__ cen,
    const float* __restrict__ ls, const float* __restrict__ W,
    const float* __restrict__ bias,
    signed char* __restrict__ xq, signed char* __restrict__ cq,
    unsigned short* __restrict__ wb,
    float* __restrict__ x2, float* __restrict__ c2, float* __restrict__ sc,
    float* __restrict__ out) {
  const int bx = blockIdx.x;
  if (bx < B_ROWS / 4) {
    conv_row(x, xq, x2, bx * 4 + (threadIdx.x >> 6), threadIdx.x & 63);
  } else if (bx < B_ROWS / 4 + C_DIM / 4) {
    conv_row(cen, cq, c2, (bx - B_ROWS / 4) * 4 + (threadIdx.x >> 6), threadIdx.x & 63);
  } else {
    const int i = (bx - (B_ROWS / 4 + C_DIM / 4)) * 256 + threadIdx.x;
    if (i < B_ROWS * NOUT) out[i] = bias[i % NOUT];
    const int j = i - B_ROWS * NOUT;
    if (j >= 0 && j < 16 * C_DIM)
      wb[j] = ((j >> 11) < NOUT) ? f2bf(W[(j >> 11) * C_DIM + (j & 2047)]) : (unsigned short)0;
    const int k = j - 16 * C_DIM;
    if (k >= 0 && k < C_DIM) sc[k] = __expf(-2.f * ls[k]);
  }
}

// --- main fused kernel: 128x128 tile over (B,C), BK=128 i8, 4 waves 2x2.
// LDS union: [ As(16K) | Bs(16K) ] overlaid by Ph(34K); + 1.5K f32 vectors.
// 36.3KB -> 4 blocks/CU (cross-block LDS/MFMA pipe overlap, proven 36%).
__global__ __launch_bounds__(256, 4) void rbf_main(
    const signed char* __restrict__ xq, const signed char* __restrict__ cq,
    const unsigned short* __restrict__ wb,
    const float* __restrict__ x2, const float* __restrict__ c2,
    const float* __restrict__ scale, float* __restrict__ out) {
  __shared__ char smem[34816];               // max(32768 stage, 34816 Ph)
  signed char* As = (signed char*)smem;                  // 128 x 128 i8
  signed char* Bs = (signed char*)(smem + 16384);        // 128 x 128 i8
  unsigned short* Ph = (unsigned short*)smem;            // 128 x 136 shorts
  __shared__ float x2s[128], c2s[128], scs[128];

  const int tid  = threadIdx.x;
  const int w    = tid >> 6;
  const int lane = tid & 63;
  const int q    = lane >> 4;
  const int l16  = lane & 15;
  const int brow = blockIdx.x * 128;
  const int bcol = blockIdx.y * 128;

  if (tid < 128) x2s[tid] = x2[brow + tid];
  else { c2s[tid - 128] = c2[bcol + tid - 128]; scs[tid - 128] = scale[bcol + tid - 128]; }

  // staging: thread t covers (row = r*32 + t/8, 16B-octet (t&7) ^ (row&7))
  // per issue r. Same proven swizzle as bf16/BK=64: rows are 128B = 8 octets
  // of 16B; XOR on the GLOBAL source, LDS linear, undone on the read side.
  const int srow = tid >> 3;                       // 0..31
  const int skc  = (tid & 7) ^ (srow & 7);         // swizzled 16B-octet
  const signed char* gA = xq + (size_t)(brow + srow) * KPAD + skc * 16;
  const signed char* gB = cq + (size_t)(bcol + srow) * KPAD + skc * 16;
  signed char* lA = As + w * 1024;                 // + r*4096 per issue (bytes)
  signed char* lB = Bs + w * 1024;

  const int wr = (w >> 1) * 64;  // wave row offset in tile
  const int wc = (w & 1) * 64;   // wave col offset
  const int swz = l16 & 7;

  i32x4 acc[4][4] = {};

  for (int t = 0; t < NT; ++t) {
    const int k0 = t * BK;                         // byte offset in row
#pragma unroll
    for (int r = 0; r < 4; ++r) {
      async16(gA + (size_t)r * 32 * KPAD + k0, lA + r * 4096);
      async16(gB + (size_t)r * 32 * KPAD + k0, lB + r * 4096);
    }
    __syncthreads();  // drains vmcnt (global_load_lds) per barrier semantics
#pragma unroll
    for (int ks = 0; ks < 2; ++ks) {               // ks = K-64 half of tile
      i32x4 af[4], bfr[4];
#pragma unroll
      for (int i = 0; i < 4; ++i)
        af[i] = *(const i32x4*)&As[(wr + i * 16 + l16) * 128 + (((ks * 4 + q) ^ swz) << 4)];
#pragma unroll
      for (int j = 0; j < 4; ++j)
        bfr[j] = *(const i32x4*)&Bs[(wc + j * 16 + l16) * 128 + (((ks * 4 + q) ^ swz) << 4)];
#pragma unroll
      for (int i = 0; i < 4; ++i)
#pragma unroll
        for (int j = 0; j < 4; ++j)
          acc[i][j] = __builtin_amdgcn_mfma_i32_16x16x64_i8(af[i], bfr[j], acc[i][j], 0, 0, 0);
    }
    __syncthreads();
  }

  // epilogue 1: d2 -> phi -> Ph (bf16), overlaying the dead stage buffers.
  // C/D layout (dtype-independent): col=lane&15, row=q*4+r.
  // d2 = ||x||^2 + ||c||^2 - 2*s^2*dot_i8  (norms exact fp32, dot exact i32)
#pragma unroll
  for (int i = 0; i < 4; ++i) {
#pragma unroll
    for (int j = 0; j < 4; ++j) {
      const int cl = wc + j * 16 + l16;
      const float c2v = c2s[cl];
      const float sc = scs[cl];
#pragma unroll
      for (int r = 0; r < 4; ++r) {
        const int rl = wr + i * 16 + q * 4 + r;
        float d2 = x2s[rl] + c2v - TWO_S2 * (float)acc[i][j][r];
        d2 = fmaxf(d2, 0.f);
        const float phi = __expf(-d2 * sc);
        Ph[rl * 136 + cl] = f2bf(phi);
      }
    }
  }
  __syncthreads();

  // epilogue 2: out_tile(128x10) = Ph(128x128) @ Wb(16-row slice)^T, K=128.
  // wave w handles rows w*32 .. w*32+31 (2 M-frags). bf16 path unchanged.
  f32x4 oacc[2] = {};
#pragma unroll
  for (int kk = 0; kk < 4; ++kk) {
    const bf16x8 bw = *(const bf16x8*)&wb[(size_t)l16 * C_DIM + bcol + kk * 32 + q * 8];
#pragma unroll
    for (int mi = 0; mi < 2; ++mi) {
      const bf16x8 ap = *(const bf16x8*)&Ph[(w * 32 + mi * 16 + l16) * 136 + kk * 32 + q * 8];
      oacc[mi] = __builtin_amdgcn_mfma_f32_16x16x32_bf16(ap, bw, oacc[mi], 0, 0, 0);
    }
  }
  if (l16 < NOUT) {
#pragma unroll
    for (int mi = 0; mi < 2; ++mi)
#pragma unroll
      for (int r = 0; r < 4; ++r) {
        const int grow = brow + w * 32 + mi * 16 + q * 4 + r;
        atomicAdd(&out[grow * NOUT + l16], oacc[mi][r]);
      }
  }
}

extern "C" void kernel_launch(void* const* d_in, const int* in_sizes, int n_in,
                              void* d_out, int out_size, void* d_ws, size_t ws_size,
                              hipStream_t stream) {
  const float* x    = (const float*)d_in[0];  // (16384,784)
  const float* cen  = (const float*)d_in[1];  // (2048,784)
  const float* ls   = (const float*)d_in[2];  // (2048,)
  const float* W    = (const float*)d_in[3];  // (10,2048)
  const float* bias = (const float*)d_in[4];  // (10,)
  float* out = (float*)d_out;                 // (16384,10)

  unsigned char* ws = (unsigned char*)d_ws;
  signed char* xq = (signed char*)(ws);                   // 16384*896 = 14,680,064
  signed char* cq = (signed char*)(ws + 14680064);        //  2048*896 =  1,835,008
  unsigned short* wb = (unsigned short*)(ws + 16515072);  //   16*2048*2 =   65,536
  float* x2 = (float*)(ws + 16580608);                    // 16384*4
  float* c2 = (float*)(ws + 16646144);                    //  2048*4
  float* sc = (float*)(ws + 16654336);                    //  2048*4  (end 16,662,528)

  const int prep_blocks = B_ROWS / 4 + C_DIM / 4 +
                          (B_ROWS * NOUT + 16 * C_DIM + C_DIM + 255) / 256;
  prep_all<<<prep_blocks, 256, 0, stream>>>(x, cen, ls, W, bias, xq, cq, wb, x2, c2, sc, out);
  rbf_main<<<dim3(B_ROWS / 128, C_DIM / 128), 256, 0, stream>>>(xq, cq, wb, x2, c2, sc, out);
}